// Round 3
// baseline (122.761 us; speedup 1.0000x reference)
//
#include <hip/hip_runtime.h>
#include <math.h>
#include <stdint.h>

#define N 1024
#define D 512
#define MAXNEG 64
#define HALF_CNT (1u << 19)  // (N*N)/2 = 524288

// ---------------------------------------------------------------------------
// Threefry-2x32-20, key = (0,1) (jax.random.key(1)). jax uniform(n,n) counter
// layout (original, non-partitionable): pair (f, f+HALF) produces
// noise[flat=f] = x0_out and noise[flat=f+HALF] = x1_out. Since row i < 512
// has f = i*N+j < 2^19, ONE eval yields noise for rows i and i+512 at col j.
// Uniform value is monotonic in (bits >> 9) — all top-k needs.
// ---------------------------------------------------------------------------
__device__ __forceinline__ uint32_t rotl32(uint32_t x, uint32_t r) {
    return (x << r) | (x >> (32u - r));
}

__device__ __forceinline__ uint2 tf_pair(uint32_t f) {
    const uint32_t K0 = 0u, K1 = 1u;
    const uint32_t KS2 = 0x1BD11BDBu;  // 0x1BD11BDA ^ K0 ^ K1
    uint32_t x0 = f, x1 = f + HALF_CNT;
    x0 += K0; x1 += K1;
#define TFR(r) { x0 += x1; x1 = rotl32(x1, (r)); x1 ^= x0; }
    TFR(13) TFR(15) TFR(26) TFR(6)
    x0 += K1;  x1 += KS2 + 1u;
    TFR(17) TFR(29) TFR(16) TFR(24)
    x0 += KS2; x1 += K0 + 2u;
    TFR(13) TFR(15) TFR(26) TFR(6)
    x0 += K0;  x1 += K1 + 3u;
    TFR(17) TFR(29) TFR(16) TFR(24)
    x0 += K1;  x1 += KS2 + 4u;
    TFR(13) TFR(15) TFR(26) TFR(6)
    x0 += KS2; x1 += K0 + 5u;
#undef TFR
    return make_uint2(x0, x1);
}

__device__ __forceinline__ unsigned long long shflx_u64(unsigned long long v, int m) {
    unsigned lo = (unsigned)(v & 0xffffffffull);
    unsigned hi = (unsigned)(v >> 32);
    lo = __shfl_xor(lo, m, 64);
    hi = __shfl_xor(hi, m, 64);
    return ((unsigned long long)hi << 32) | (unsigned long long)lo;
}

// ---------------------------------------------------------------------------
// K1: inverse L2 norms (4 waves/block, one row per wave) + zero-init of the
// global accumulators used by the fused finalization in k_rowloss.
// ---------------------------------------------------------------------------
__global__ __launch_bounds__(256) void k_norms(const float* __restrict__ V,
                                               float* __restrict__ inv,
                                               float* __restrict__ gsum,
                                               float* __restrict__ gcnt,
                                               unsigned* __restrict__ done) {
    if (blockIdx.x == 0 && threadIdx.x == 0) { *gsum = 0.0f; *gcnt = 0.0f; *done = 0u; }
    const int w = threadIdx.x >> 6, l = threadIdx.x & 63;
    const int r = blockIdx.x * 4 + w;
    const float4* vp = (const float4*)(V + (size_t)r * D);
    float4 a = vp[l], b = vp[l + 64];
    float ss = a.x*a.x + a.y*a.y + a.z*a.z + a.w*a.w
             + b.x*b.x + b.y*b.y + b.z*b.z + b.w*b.w;
#pragma unroll
    for (int off = 32; off > 0; off >>= 1) ss += __shfl_xor(ss, off, 64);
    if (l == 0) inv[r] = 1.0f / sqrtf(ss);
}

// ---------------------------------------------------------------------------
// K2: K-split GEMM. Split s computes partial sim over K-range
// [z*D/S, (z+1)*D/S) into simbase + z*N*N (scaled partials sum linearly).
// S=4 -> 1024 blocks = 4 waves/SIMD (fixes the 1-wave/SIMD latency exposure
// of the unsplit 256-block version). 64x64 tile, KC=32, 4x4 micro-tile.
// LDS transposed (stride 68) so fragment reads are ds_read_b128
// (a: 16-lane broadcast, b: 2-way = free); transpose-writes ~4-way (1.58x)
// but only 16 scalar writes/thread/tile. Register prefetch of next tile.
// ---------------------------------------------------------------------------
template <int S>
__global__ __launch_bounds__(256) void k_simgemm(const float* __restrict__ V,
                                                 const float* __restrict__ inv,
                                                 float* __restrict__ simbase) {
    constexpr int KS = D / S;
    constexpr int NT = KS / 32;
    __shared__ __align__(16) float Ast[32][68];
    __shared__ __align__(16) float Bst[32][68];
    const int t  = threadIdx.x;
    const int bi = blockIdx.y, bj = blockIdx.x, z = blockIdx.z;
    float* sim = simbase + (size_t)z * (N * N);
    const int lr = t >> 3, lc = (t & 7) * 4;  // loader: row, col(float4)*4
    const int ty = t >> 4, tx = t & 15;       // compute: 16x16 thread grid

    float acc[4][4] = {};
    const float* Abase = V + (size_t)(bi * 64) * D + z * KS;
    const float* Bbase = V + (size_t)(bj * 64) * D + z * KS;

    float4 a0 = *(const float4*)(Abase + (size_t)lr        * D + lc);
    float4 a1 = *(const float4*)(Abase + (size_t)(lr + 32) * D + lc);
    float4 b0 = *(const float4*)(Bbase + (size_t)lr        * D + lc);
    float4 b1 = *(const float4*)(Bbase + (size_t)(lr + 32) * D + lc);

    for (int kt = 0; kt < NT; ++kt) {
        Ast[lc + 0][lr] = a0.x; Ast[lc + 1][lr] = a0.y;
        Ast[lc + 2][lr] = a0.z; Ast[lc + 3][lr] = a0.w;
        Ast[lc + 0][lr + 32] = a1.x; Ast[lc + 1][lr + 32] = a1.y;
        Ast[lc + 2][lr + 32] = a1.z; Ast[lc + 3][lr + 32] = a1.w;
        Bst[lc + 0][lr] = b0.x; Bst[lc + 1][lr] = b0.y;
        Bst[lc + 2][lr] = b0.z; Bst[lc + 3][lr] = b0.w;
        Bst[lc + 0][lr + 32] = b1.x; Bst[lc + 1][lr + 32] = b1.y;
        Bst[lc + 2][lr + 32] = b1.z; Bst[lc + 3][lr + 32] = b1.w;
        __syncthreads();

        const bool has_next = (kt + 1) < NT;
        float4 na0, na1, nb0, nb1;
        if (has_next) {  // land during compute
            const int k0 = (kt + 1) * 32;
            na0 = *(const float4*)(Abase + (size_t)lr        * D + k0 + lc);
            na1 = *(const float4*)(Abase + (size_t)(lr + 32) * D + k0 + lc);
            nb0 = *(const float4*)(Bbase + (size_t)lr        * D + k0 + lc);
            nb1 = *(const float4*)(Bbase + (size_t)(lr + 32) * D + k0 + lc);
        }

#pragma unroll
        for (int kk = 0; kk < 32; ++kk) {
            const float4 av = *(const float4*)&Ast[kk][ty * 4];
            const float4 bv = *(const float4*)&Bst[kk][tx * 4];
            const float a[4] = {av.x, av.y, av.z, av.w};
            const float b[4] = {bv.x, bv.y, bv.z, bv.w};
#pragma unroll
            for (int u = 0; u < 4; ++u)
#pragma unroll
                for (int v = 0; v < 4; ++v) acc[u][v] += a[u] * b[v];
        }
        __syncthreads();
        if (has_next) { a0 = na0; a1 = na1; b0 = nb0; b1 = nb1; }
    }

    const int col = bj * 64 + tx * 4;
    float ic[4];
#pragma unroll
    for (int v = 0; v < 4; ++v) ic[v] = inv[col + v];
#pragma unroll
    for (int u = 0; u < 4; ++u) {
        const int row = bi * 64 + ty * 4 + u;
        const float ir = inv[row];
        float4 o;
        o.x = acc[u][0] * ir * ic[0];
        o.y = acc[u][1] * ir * ic[1];
        o.z = acc[u][2] * ir * ic[2];
        o.w = acc[u][3] * ir * ic[3];
        *(float4*)(sim + (size_t)row * N + col) = o;
    }
}

// ---------------------------------------------------------------------------
// K3: paired per-row loss. Block b handles rows i0=b and i1=b+512 (they share
// all Threefry evals: x0 -> row i0, x1 -> row i1). 512 blocks, 4 waves each.
//  phase 1: sum split sim rows into LDS; keys + per-row 256-bucket histogram
//  phase 2a: two block suffix-scans -> threshold bucket B, remainder r per row
//  phase 2b: parallel select bucket>B (set semantics; order-free);
//            boundary bucket collected to list
//  phase 2c: serial top-r in boundary bucket; wave 0 <- row i0, wave 1 <- row i1
//  phase 3: sum softplus(ns-ps) = log prod(1 + e^ns * e^-ps): 2 VALU/pair, no
//           transcendentals in the loop. Invalid pos slot: ei=0 -> prod stays
//           exactly 1.0 -> log exactly 0 (bit-exact masking).
//  final: last-block pattern folds the 1024-row mean into this kernel.
// ---------------------------------------------------------------------------
template <int S>
__global__ __launch_bounds__(256) void k_rowloss(const float* __restrict__ simbase,
                                                 const int* __restrict__ labels,
                                                 float* __restrict__ gsum,
                                                 float* __restrict__ gcnt,
                                                 unsigned* __restrict__ done,
                                                 float* __restrict__ out) {
    __shared__ __align__(16) float simrow0[N];
    __shared__ __align__(16) float simrow1[N];
    __shared__ int   hist0[256], hist1[256];
    __shared__ unsigned long long list0[256], list1[256];
    __shared__ float ens0[MAXNEG], ens1[MAXNEG];
    __shared__ int   wpart0[4], wpart1[4];
    __shared__ float wsA[4], wsB[4];
    __shared__ int   wpA[4], wpB[4];
    __shared__ int   s_B0, s_r0, s_cnt0, s_lcnt0;
    __shared__ int   s_B1, s_r1, s_cnt1, s_lcnt1;

    const int b = blockIdx.x;
    const int i0 = b, i1 = b + 512;
    const int t = threadIdx.x;
    const int lane = t & 63, w = t >> 6;
    const int jb = t * 4;

    if (t == 0) {
        s_B0 = -1; s_r0 = 0; s_cnt0 = 0; s_lcnt0 = 0;
        s_B1 = -1; s_r1 = 0; s_cnt1 = 0; s_lcnt1 = 0;
    }
    hist0[t] = 0; hist1[t] = 0;

    // ---- phase 1: sum split partials into LDS rows ----
    {
        float4 s0 = ((const float4*)(simbase + (size_t)i0 * N))[t];
        float4 s1 = ((const float4*)(simbase + (size_t)i1 * N))[t];
#pragma unroll
        for (int s = 1; s < S; ++s) {
            const float4 x0 = ((const float4*)(simbase + (size_t)s * N * N + (size_t)i0 * N))[t];
            const float4 x1 = ((const float4*)(simbase + (size_t)s * N * N + (size_t)i1 * N))[t];
            s0.x += x0.x; s0.y += x0.y; s0.z += x0.z; s0.w += x0.w;
            s1.x += x1.x; s1.y += x1.y; s1.z += x1.z; s1.w += x1.w;
        }
        ((float4*)simrow0)[t] = s0;
        ((float4*)simrow1)[t] = s1;
    }
    const int labi0 = labels[i0], labi1 = labels[i1];
    int4 lv = ((const int4*)labels)[t];
    const int ljs[4] = {lv.x, lv.y, lv.z, lv.w};

    int npos0 = 0, npos1 = 0;
    unsigned long long kq0[4], kq1[4];
    __syncthreads();  // hist zero + s_* init visible before atomics
#pragma unroll
    for (int q = 0; q < 4; ++q) {
        const int j = jb + q;
        const uint2 rb = tf_pair((uint32_t)(i0 * N + j));
        const bool eq0 = (ljs[q] == labi0), eq1 = (ljs[q] == labi1);
        npos0 += (eq0 && j != i0) ? 1 : 0;
        npos1 += (eq1 && j != i1) ? 1 : 0;
        unsigned long long key0 = 0ull, key1 = 0ull;
        if (!eq0) {  // (value desc, index asc); valid keys >= 1024 > 0
            key0 = ((unsigned long long)(rb.x >> 9) << 11)
                 | (unsigned long long)(2047 - j);
            atomicAdd(&hist0[(int)(key0 >> 26)], 1);
        }
        if (!eq1) {
            key1 = ((unsigned long long)(rb.y >> 9) << 11)
                 | (unsigned long long)(2047 - j);
            atomicAdd(&hist1[(int)(key1 >> 26)], 1);
        }
        kq0[q] = key0; kq1[q] = key1;
    }
    __syncthreads();

    // ---- phase 2a: two suffix scans (bucket 255-t), block-wide ----
    {
        const int own0 = hist0[255 - t], own1 = hist1[255 - t];
        int v0 = own0, v1 = own1;
#pragma unroll
        for (int off = 1; off < 64; off <<= 1) {
            const int u0 = __shfl_up(v0, off, 64);
            const int u1 = __shfl_up(v1, off, 64);
            if (lane >= off) { v0 += u0; v1 += u1; }
        }
        if (lane == 63) { wpart0[w] = v0; wpart1[w] = v1; }
        __syncthreads();
        int add0 = 0, add1 = 0;
#pragma unroll
        for (int k = 0; k < 4; ++k) {
            add0 += (k < w) ? wpart0[k] : 0;
            add1 += (k < w) ? wpart1[k] : 0;
        }
        v0 += add0; v1 += add1;  // S[b], b = 255 - t
        if (v0 >= MAXNEG && v0 - own0 < MAXNEG) { s_B0 = 255 - t; s_r0 = MAXNEG - (v0 - own0); }
        if (v1 >= MAXNEG && v1 - own1 < MAXNEG) { s_B1 = 255 - t; s_r1 = MAXNEG - (v1 - own1); }
    }
    __syncthreads();

    // ---- phase 2b: parallel above-threshold select; collect boundary bucket --
    const int B0 = s_B0, B1 = s_B1;
#pragma unroll
    for (int q = 0; q < 4; ++q) {
        const unsigned long long key0 = kq0[q], key1 = kq1[q];
        if (key0 != 0ull) {
            const int bk = (int)(key0 >> 26);
            if (bk > B0) {
                const int slot = atomicAdd(&s_cnt0, 1);
                ens0[slot] = __expf(simrow0[2047 - (int)(key0 & 2047ull)] / 10.0f);
            } else if (bk == B0) {
                const int slot = atomicAdd(&s_lcnt0, 1);
                if (slot < 256) list0[slot] = key0;
            }
        }
        if (key1 != 0ull) {
            const int bk = (int)(key1 >> 26);
            if (bk > B1) {
                const int slot = atomicAdd(&s_cnt1, 1);
                ens1[slot] = __expf(simrow1[2047 - (int)(key1 & 2047ull)] / 10.0f);
            } else if (bk == B1) {
                const int slot = atomicAdd(&s_lcnt1, 1);
                if (slot < 256) list1[slot] = key1;
            }
        }
    }
    __syncthreads();

    // ---- phase 2c: serial top-r in boundary bucket; wave w handles row w ----
    if (w < 2) {
        const int rr = (w == 0) ? s_r0 : s_r1;
        if (rr > 0) {
            const unsigned long long* lst = (w == 0) ? list0 : list1;
            const int   m    = min((w == 0) ? s_lcnt0 : s_lcnt1, 256);
            const int   base = (w == 0) ? s_cnt0 : s_cnt1;
            float*      ensw = (w == 0) ? ens0 : ens1;
            const float* srw = (w == 0) ? simrow0 : simrow1;
            unsigned long long lk[4];
#pragma unroll
            for (int q = 0; q < 4; ++q) {
                const int idx = lane + q * 64;
                lk[q] = (idx < m) ? lst[idx] : 0ull;
            }
            for (int it = 0; it < rr; ++it) {
                unsigned long long mx = lk[0];
#pragma unroll
                for (int q = 1; q < 4; ++q) mx = lk[q] > mx ? lk[q] : mx;
#pragma unroll
                for (int off = 1; off < 64; off <<= 1) {
                    const unsigned long long o = shflx_u64(mx, off);
                    mx = o > mx ? o : mx;
                }
#pragma unroll
                for (int q = 0; q < 4; ++q) if (lk[q] == mx) lk[q] = 0ull;
                if (lane == 0)
                    ensw[base + it] = __expf(srw[2047 - (int)(mx & 2047ull)] / 10.0f);
            }
        }
    }
    __syncthreads();
    const int nneg0 = s_cnt0 + s_r0;  // == min(64, #negatives of row i0)
    const int nneg1 = s_cnt1 + s_r1;

    // ---- phase 3: product-form pair accumulation (both rows) ----
    float ei0[4], ei1[4];
#pragma unroll
    for (int q = 0; q < 4; ++q) {
        const int j = jb + q;
        ei0[q] = (ljs[q] == labi0 && j != i0) ? __expf(-simrow0[j] / 5.0f) : 0.0f;
        ei1[q] = (ljs[q] == labi1 && j != i1) ? __expf(-simrow1[j] / 5.0f) : 0.0f;
    }
    float p00 = 1.0f, p01 = 1.0f, p02 = 1.0f, p03 = 1.0f;
#pragma unroll 8
    for (int k = 0; k < nneg0; ++k) {
        const float e = ens0[k];
        p00 *= fmaf(e, ei0[0], 1.0f);
        p01 *= fmaf(e, ei0[1], 1.0f);
        p02 *= fmaf(e, ei0[2], 1.0f);
        p03 *= fmaf(e, ei0[3], 1.0f);
    }
    float p10 = 1.0f, p11 = 1.0f, p12 = 1.0f, p13 = 1.0f;
#pragma unroll 8
    for (int k = 0; k < nneg1; ++k) {
        const float e = ens1[k];
        p10 *= fmaf(e, ei1[0], 1.0f);
        p11 *= fmaf(e, ei1[1], 1.0f);
        p12 *= fmaf(e, ei1[2], 1.0f);
        p13 *= fmaf(e, ei1[3], 1.0f);
    }
    float r0 = __logf(p00) + __logf(p01) + __logf(p02) + __logf(p03);
    float r1 = __logf(p10) + __logf(p11) + __logf(p12) + __logf(p13);

#pragma unroll
    for (int off = 32; off > 0; off >>= 1) {
        r0 += __shfl_xor(r0, off, 64);
        r1 += __shfl_xor(r1, off, 64);
        npos0 += __shfl_xor(npos0, off, 64);
        npos1 += __shfl_xor(npos1, off, 64);
    }
    if (lane == 0) { wsA[w] = r0; wsB[w] = r1; wpA[w] = npos0; wpB[w] = npos1; }
    __syncthreads();
    if (t == 0) {
        const float rs0 = wsA[0] + wsA[1] + wsA[2] + wsA[3];
        const float rs1 = wsB[0] + wsB[1] + wsB[2] + wsB[3];
        const int   np0 = wpA[0] + wpA[1] + wpA[2] + wpA[3];
        const int   np1 = wpB[0] + wpB[1] + wpB[2] + wpB[3];
        const float rl0 = (np0 > 0) ? rs0 / fmaxf((float)np0 * (float)nneg0, 1.0f) : 0.0f;
        const float rl1 = (np1 > 0) ? rs1 / fmaxf((float)np1 * (float)nneg1, 1.0f) : 0.0f;
        const float hp  = (np0 > 0 ? 1.0f : 0.0f) + (np1 > 0 ? 1.0f : 0.0f);
        atomicAdd(gsum, rl0 + rl1);
        atomicAdd(gcnt, hp);
        __threadfence();
        const unsigned old = atomicAdd(done, 1u);
        if (old == (N / 2) - 1) {  // last block: coherent readback via atomic RMW
            const float Sv = atomicAdd(gsum, 0.0f);
            const float Cv = atomicAdd(gcnt, 0.0f);
            out[0] = (Cv > 0.0f) ? Sv / fmaxf(Cv, 1.0f) : 0.0f;
        }
    }
}

extern "C" void kernel_launch(void* const* d_in, const int* in_sizes, int n_in,
                              void* d_out, int out_size, void* d_ws, size_t ws_size,
                              hipStream_t stream) {
    const float* V      = (const float*)d_in[0];
    const int*   labels = (const int*)d_in[1];
    float* out = (float*)d_out;

    char* ws = (char*)d_ws;
    float*    inv  = (float*)(ws);                 // 4 KB
    float*    gsum = (float*)(ws + 4096);
    float*    gcnt = (float*)(ws + 4096 + 16);
    unsigned* done = (unsigned*)(ws + 4096 + 32);
    float*    sim  = (float*)(ws + 8192);          // S x 4 MB partial buffers

    const size_t simbytes = (size_t)N * N * sizeof(float);
    // ws_size is call-invariant -> same kernel sequence every call (capture-safe)
    const int S = (ws_size >= 8192 + 4 * simbytes) ? 4
                : (ws_size >= 8192 + 2 * simbytes) ? 2 : 1;

    k_norms<<<N / 4, 256, 0, stream>>>(V, inv, gsum, gcnt, done);
    if (S == 4) {
        k_simgemm<4><<<dim3(N / 64, N / 64, 4), 256, 0, stream>>>(V, inv, sim);
        k_rowloss<4><<<N / 2, 256, 0, stream>>>(sim, labels, gsum, gcnt, done, out);
    } else if (S == 2) {
        k_simgemm<2><<<dim3(N / 64, N / 64, 2), 256, 0, stream>>>(V, inv, sim);
        k_rowloss<2><<<N / 2, 256, 0, stream>>>(sim, labels, gsum, gcnt, done, out);
    } else {
        k_simgemm<1><<<dim3(N / 64, N / 64, 1), 256, 0, stream>>>(V, inv, sim);
        k_rowloss<1><<<N / 2, 256, 0, stream>>>(sim, labels, gsum, gcnt, done, out);
    }
}

// Round 4
// 97.261 us; speedup vs baseline: 1.2622x; 1.2622x over previous
//
#include <hip/hip_runtime.h>
#include <hip/hip_bf16.h>
#include <math.h>
#include <stdint.h>

#define N 1024
#define D 512
#define MAXNEG 64
#define HALF_CNT (1u << 19)  // (N*N)/2 = 524288

typedef __attribute__((ext_vector_type(8))) short short8;  // 8 bf16 = 4 VGPR
typedef __attribute__((ext_vector_type(4))) float f32x4;

// ---------------------------------------------------------------------------
// Threefry-2x32-20, key = (0,1) (jax.random.key(1)). jax uniform(n,n) counter
// layout (original, non-partitionable): pair (f, f+HALF) produces
// noise[flat=f] = x0_out and noise[flat=f+HALF] = x1_out. Row i < 512 has
// f = i*N+j < 2^19, so ONE eval yields noise for rows i and i+512 at col j.
// Verified bit-exact on HW (round 3: absmax == 0.0).
// ---------------------------------------------------------------------------
__device__ __forceinline__ uint32_t rotl32(uint32_t x, uint32_t r) {
    return (x << r) | (x >> (32u - r));
}

__device__ __forceinline__ uint2 tf_pair(uint32_t f) {
    const uint32_t K0 = 0u, K1 = 1u;
    const uint32_t KS2 = 0x1BD11BDBu;  // 0x1BD11BDA ^ K0 ^ K1
    uint32_t x0 = f, x1 = f + HALF_CNT;
    x0 += K0; x1 += K1;
#define TFR(r) { x0 += x1; x1 = rotl32(x1, (r)); x1 ^= x0; }
    TFR(13) TFR(15) TFR(26) TFR(6)
    x0 += K1;  x1 += KS2 + 1u;
    TFR(17) TFR(29) TFR(16) TFR(24)
    x0 += KS2; x1 += K0 + 2u;
    TFR(13) TFR(15) TFR(26) TFR(6)
    x0 += K0;  x1 += K1 + 3u;
    TFR(17) TFR(29) TFR(16) TFR(24)
    x0 += K1;  x1 += KS2 + 4u;
    TFR(13) TFR(15) TFR(26) TFR(6)
    x0 += KS2; x1 += K0 + 5u;
#undef TFR
    return make_uint2(x0, x1);
}

__device__ __forceinline__ unsigned long long shflx_u64(unsigned long long v, int m) {
    unsigned lo = (unsigned)(v & 0xffffffffull);
    unsigned hi = (unsigned)(v >> 32);
    lo = __shfl_xor(lo, m, 64);
    hi = __shfl_xor(hi, m, 64);
    return ((unsigned long long)hi << 32) | (unsigned long long)lo;
}

__device__ __forceinline__ ushort f2bf(float x) {
    __hip_bfloat16 h = __float2bfloat16(x);
    return *(ushort*)&h;
}

// ---------------------------------------------------------------------------
// K1: inverse L2 norms (f32, exact) + V -> bf16 conversion + accumulator init.
// 4 waves/block, one row per wave.
// ---------------------------------------------------------------------------
__global__ __launch_bounds__(256) void k_norms(const float* __restrict__ V,
                                               float* __restrict__ inv,
                                               ushort* __restrict__ Vh,
                                               float* __restrict__ gsum,
                                               float* __restrict__ gcnt,
                                               unsigned* __restrict__ done) {
    if (blockIdx.x == 0 && threadIdx.x == 0) { *gsum = 0.0f; *gcnt = 0.0f; *done = 0u; }
    const int w = threadIdx.x >> 6, l = threadIdx.x & 63;
    const int r = blockIdx.x * 4 + w;
    const float4* vp = (const float4*)(V + (size_t)r * D);
    float4 a = vp[l], b = vp[l + 64];
    float ss = a.x*a.x + a.y*a.y + a.z*a.z + a.w*a.w
             + b.x*b.x + b.y*b.y + b.z*b.z + b.w*b.w;
#pragma unroll
    for (int off = 32; off > 0; off >>= 1) ss += __shfl_xor(ss, off, 64);
    if (l == 0) inv[r] = 1.0f / sqrtf(ss);
    ushort4 ua, ub;
    ua.x = f2bf(a.x); ua.y = f2bf(a.y); ua.z = f2bf(a.z); ua.w = f2bf(a.w);
    ub.x = f2bf(b.x); ub.y = f2bf(b.y); ub.z = f2bf(b.z); ub.w = f2bf(b.w);
    *(ushort4*)(Vh + (size_t)r * D + 4 * l)       = ua;
    *(ushort4*)(Vh + (size_t)r * D + 256 + 4 * l) = ub;
}

// ---------------------------------------------------------------------------
// K2: raw dot GEMM via bf16 MFMA (16x16x32). One wave per 64x64 tile, full K,
// NO LDS: fragments load straight from global (L2-resident, 1 MB).
// Operand layout (gfx950 mfma_f32_16x16x32_bf16): lane l holds row/col (l&15),
// k = (l>>4)*8 + e, e contiguous -> a 16B short8 load IS the fragment.
// C/D layout (m89-verified): col = lane&15, row = (lane>>4)*4 + reg.
// 1-deep software pipeline: next K-step's 8 loads issue before current MFMAs.
// ---------------------------------------------------------------------------
__global__ __launch_bounds__(64) void k_gemm(const ushort* __restrict__ Vh,
                                             float* __restrict__ sim) {
    const int l  = threadIdx.x;
    const int bi = blockIdx.y, bj = blockIdx.x;
    const int lr = l & 15, lk = (l >> 4) * 8;

    const ushort* Ab = Vh + (size_t)(bi * 64 + lr) * D + lk;
    const ushort* Bb = Vh + (size_t)(bj * 64 + lr) * D + lk;

    f32x4 acc[4][4];
#pragma unroll
    for (int m = 0; m < 4; ++m)
#pragma unroll
        for (int n = 0; n < 4; ++n) acc[m][n] = (f32x4){0.f, 0.f, 0.f, 0.f};

    short8 a[4], b[4], na[4], nb[4];
#pragma unroll
    for (int m = 0; m < 4; ++m) a[m] = *(const short8*)(Ab + (size_t)m * 16 * D);
#pragma unroll
    for (int n = 0; n < 4; ++n) b[n] = *(const short8*)(Bb + (size_t)n * 16 * D);

    for (int k0 = 32; k0 <= D; k0 += 32) {
        if (k0 < D) {  // prefetch next K-step
#pragma unroll
            for (int m = 0; m < 4; ++m) na[m] = *(const short8*)(Ab + (size_t)m * 16 * D + k0);
#pragma unroll
            for (int n = 0; n < 4; ++n) nb[n] = *(const short8*)(Bb + (size_t)n * 16 * D + k0);
        }
#pragma unroll
        for (int m = 0; m < 4; ++m)
#pragma unroll
            for (int n = 0; n < 4; ++n)
                acc[m][n] = __builtin_amdgcn_mfma_f32_16x16x32_bf16(a[m], b[n], acc[m][n], 0, 0, 0);
        if (k0 < D) {
#pragma unroll
            for (int m = 0; m < 4; ++m) a[m] = na[m];
#pragma unroll
            for (int n = 0; n < 4; ++n) b[n] = nb[n];
        }
    }

    const int r0 = (l >> 4) * 4;  // row base within 16-block
#pragma unroll
    for (int m = 0; m < 4; ++m) {
#pragma unroll
        for (int r = 0; r < 4; ++r) {
            float* dst = sim + (size_t)(bi * 64 + m * 16 + r0 + r) * N + bj * 64 + lr;
#pragma unroll
            for (int n = 0; n < 4; ++n) dst[n * 16] = acc[m][n][r];
        }
    }
}

// ---------------------------------------------------------------------------
// K3: paired per-row loss. Block b handles rows i0=b, i1=b+512 (shared Threefry
// evals: x0 -> i0, x1 -> i1). inv_i*inv_j scaling applied at row load (GEMM
// stores raw dots). Selection machinery is bit-exact-verified (round 3).
//  phase 1: load+scale sim rows; keys + per-row 256-bucket histogram
//  phase 2a: block suffix-scan -> threshold bucket B, remainder r (per row)
//  phase 2b: parallel select bucket>B (set semantics); boundary bucket -> list
//  phase 2c: serial top-r in boundary bucket (wave 0 <- row0, wave 1 <- row1)
//  phase 3: sum softplus(ns-ps) = log prod(1 + e^ns * e^-ps); ei=0 for invalid
//           slots keeps prod exactly 1.0 -> log exactly 0 (bit-exact masking)
//  final: last-block folds the mean (atomic RMW readback for XCD coherence).
// ---------------------------------------------------------------------------
__global__ __launch_bounds__(256) void k_rowloss(const float* __restrict__ sim,
                                                 const float* __restrict__ inv,
                                                 const int* __restrict__ labels,
                                                 float* __restrict__ gsum,
                                                 float* __restrict__ gcnt,
                                                 unsigned* __restrict__ done,
                                                 float* __restrict__ out) {
    __shared__ __align__(16) float simrow0[N];
    __shared__ __align__(16) float simrow1[N];
    __shared__ int   hist0[256], hist1[256];
    __shared__ unsigned long long list0[256], list1[256];
    __shared__ float ens0[MAXNEG], ens1[MAXNEG];
    __shared__ int   wpart0[4], wpart1[4];
    __shared__ float wsA[4], wsB[4];
    __shared__ int   wpA[4], wpB[4];
    __shared__ int   s_B0, s_r0, s_cnt0, s_lcnt0;
    __shared__ int   s_B1, s_r1, s_cnt1, s_lcnt1;

    const int b = blockIdx.x;
    const int i0 = b, i1 = b + 512;
    const int t = threadIdx.x;
    const int lane = t & 63, w = t >> 6;
    const int jb = t * 4;

    if (t == 0) {
        s_B0 = -1; s_r0 = 0; s_cnt0 = 0; s_lcnt0 = 0;
        s_B1 = -1; s_r1 = 0; s_cnt1 = 0; s_lcnt1 = 0;
    }
    hist0[t] = 0; hist1[t] = 0;

    // ---- phase 1: load + scale rows into LDS ----
    {
        const float invi0 = inv[i0], invi1 = inv[i1];
        float4 s0 = ((const float4*)(sim + (size_t)i0 * N))[t];
        float4 s1 = ((const float4*)(sim + (size_t)i1 * N))[t];
        float4 iv = ((const float4*)inv)[t];
        s0.x *= invi0 * iv.x; s0.y *= invi0 * iv.y;
        s0.z *= invi0 * iv.z; s0.w *= invi0 * iv.w;
        s1.x *= invi1 * iv.x; s1.y *= invi1 * iv.y;
        s1.z *= invi1 * iv.z; s1.w *= invi1 * iv.w;
        ((float4*)simrow0)[t] = s0;
        ((float4*)simrow1)[t] = s1;
    }
    const int labi0 = labels[i0], labi1 = labels[i1];
    int4 lv = ((const int4*)labels)[t];
    const int ljs[4] = {lv.x, lv.y, lv.z, lv.w};

    int npos0 = 0, npos1 = 0;
    unsigned long long kq0[4], kq1[4];
    __syncthreads();  // hist zero + s_* init visible before atomics
#pragma unroll
    for (int q = 0; q < 4; ++q) {
        const int j = jb + q;
        const uint2 rb = tf_pair((uint32_t)(i0 * N + j));
        const bool eq0 = (ljs[q] == labi0), eq1 = (ljs[q] == labi1);
        npos0 += (eq0 && j != i0) ? 1 : 0;
        npos1 += (eq1 && j != i1) ? 1 : 0;
        unsigned long long key0 = 0ull, key1 = 0ull;
        if (!eq0) {  // (value desc, index asc); valid keys >= 1024 > 0
            key0 = ((unsigned long long)(rb.x >> 9) << 11)
                 | (unsigned long long)(2047 - j);
            atomicAdd(&hist0[(int)(key0 >> 26)], 1);
        }
        if (!eq1) {
            key1 = ((unsigned long long)(rb.y >> 9) << 11)
                 | (unsigned long long)(2047 - j);
            atomicAdd(&hist1[(int)(key1 >> 26)], 1);
        }
        kq0[q] = key0; kq1[q] = key1;
    }
    __syncthreads();

    // ---- phase 2a: two suffix scans (bucket 255-t), block-wide ----
    {
        const int own0 = hist0[255 - t], own1 = hist1[255 - t];
        int v0 = own0, v1 = own1;
#pragma unroll
        for (int off = 1; off < 64; off <<= 1) {
            const int u0 = __shfl_up(v0, off, 64);
            const int u1 = __shfl_up(v1, off, 64);
            if (lane >= off) { v0 += u0; v1 += u1; }
        }
        if (lane == 63) { wpart0[w] = v0; wpart1[w] = v1; }
        __syncthreads();
        int add0 = 0, add1 = 0;
#pragma unroll
        for (int k = 0; k < 4; ++k) {
            add0 += (k < w) ? wpart0[k] : 0;
            add1 += (k < w) ? wpart1[k] : 0;
        }
        v0 += add0; v1 += add1;  // S[b], b = 255 - t
        if (v0 >= MAXNEG && v0 - own0 < MAXNEG) { s_B0 = 255 - t; s_r0 = MAXNEG - (v0 - own0); }
        if (v1 >= MAXNEG && v1 - own1 < MAXNEG) { s_B1 = 255 - t; s_r1 = MAXNEG - (v1 - own1); }
    }
    __syncthreads();

    // ---- phase 2b: parallel above-threshold select; collect boundary bucket --
    const int B0 = s_B0, B1 = s_B1;
#pragma unroll
    for (int q = 0; q < 4; ++q) {
        const unsigned long long key0 = kq0[q], key1 = kq1[q];
        if (key0 != 0ull) {
            const int bk = (int)(key0 >> 26);
            if (bk > B0) {
                const int slot = atomicAdd(&s_cnt0, 1);
                ens0[slot] = __expf(simrow0[2047 - (int)(key0 & 2047ull)] / 10.0f);
            } else if (bk == B0) {
                const int slot = atomicAdd(&s_lcnt0, 1);
                if (slot < 256) list0[slot] = key0;
            }
        }
        if (key1 != 0ull) {
            const int bk = (int)(key1 >> 26);
            if (bk > B1) {
                const int slot = atomicAdd(&s_cnt1, 1);
                ens1[slot] = __expf(simrow1[2047 - (int)(key1 & 2047ull)] / 10.0f);
            } else if (bk == B1) {
                const int slot = atomicAdd(&s_lcnt1, 1);
                if (slot < 256) list1[slot] = key1;
            }
        }
    }
    __syncthreads();

    // ---- phase 2c: serial top-r in boundary bucket; wave w handles row w ----
    if (w < 2) {
        const int rr = (w == 0) ? s_r0 : s_r1;
        if (rr > 0) {
            const unsigned long long* lst = (w == 0) ? list0 : list1;
            const int   m    = min((w == 0) ? s_lcnt0 : s_lcnt1, 256);
            const int   base = (w == 0) ? s_cnt0 : s_cnt1;
            float*      ensw = (w == 0) ? ens0 : ens1;
            const float* srw = (w == 0) ? simrow0 : simrow1;
            unsigned long long lk[4];
#pragma unroll
            for (int q = 0; q < 4; ++q) {
                const int idx = lane + q * 64;
                lk[q] = (idx < m) ? lst[idx] : 0ull;
            }
            for (int it = 0; it < rr; ++it) {
                unsigned long long mx = lk[0];
#pragma unroll
                for (int q = 1; q < 4; ++q) mx = lk[q] > mx ? lk[q] : mx;
#pragma unroll
                for (int off = 1; off < 64; off <<= 1) {
                    const unsigned long long o = shflx_u64(mx, off);
                    mx = o > mx ? o : mx;
                }
#pragma unroll
                for (int q = 0; q < 4; ++q) if (lk[q] == mx) lk[q] = 0ull;
                if (lane == 0)
                    ensw[base + it] = __expf(srw[2047 - (int)(mx & 2047ull)] / 10.0f);
            }
        }
    }
    __syncthreads();
    const int nneg0 = s_cnt0 + s_r0;  // == min(64, #negatives of row i0)
    const int nneg1 = s_cnt1 + s_r1;

    // ---- phase 3: product-form pair accumulation (both rows) ----
    float ei0[4], ei1[4];
#pragma unroll
    for (int q = 0; q < 4; ++q) {
        const int j = jb + q;
        ei0[q] = (ljs[q] == labi0 && j != i0) ? __expf(-simrow0[j] / 5.0f) : 0.0f;
        ei1[q] = (ljs[q] == labi1 && j != i1) ? __expf(-simrow1[j] / 5.0f) : 0.0f;
    }
    float p00 = 1.0f, p01 = 1.0f, p02 = 1.0f, p03 = 1.0f;
#pragma unroll 8
    for (int k = 0; k < nneg0; ++k) {
        const float e = ens0[k];
        p00 *= fmaf(e, ei0[0], 1.0f);
        p01 *= fmaf(e, ei0[1], 1.0f);
        p02 *= fmaf(e, ei0[2], 1.0f);
        p03 *= fmaf(e, ei0[3], 1.0f);
    }
    float p10 = 1.0f, p11 = 1.0f, p12 = 1.0f, p13 = 1.0f;
#pragma unroll 8
    for (int k = 0; k < nneg1; ++k) {
        const float e = ens1[k];
        p10 *= fmaf(e, ei1[0], 1.0f);
        p11 *= fmaf(e, ei1[1], 1.0f);
        p12 *= fmaf(e, ei1[2], 1.0f);
        p13 *= fmaf(e, ei1[3], 1.0f);
    }
    float r0 = __logf(p00) + __logf(p01) + __logf(p02) + __logf(p03);
    float r1 = __logf(p10) + __logf(p11) + __logf(p12) + __logf(p13);

#pragma unroll
    for (int off = 32; off > 0; off >>= 1) {
        r0 += __shfl_xor(r0, off, 64);
        r1 += __shfl_xor(r1, off, 64);
        npos0 += __shfl_xor(npos0, off, 64);
        npos1 += __shfl_xor(npos1, off, 64);
    }
    if (lane == 0) { wsA[w] = r0; wsB[w] = r1; wpA[w] = npos0; wpB[w] = npos1; }
    __syncthreads();
    if (t == 0) {
        const float rs0 = wsA[0] + wsA[1] + wsA[2] + wsA[3];
        const float rs1 = wsB[0] + wsB[1] + wsB[2] + wsB[3];
        const int   np0 = wpA[0] + wpA[1] + wpA[2] + wpA[3];
        const int   np1 = wpB[0] + wpB[1] + wpB[2] + wpB[3];
        const float rl0 = (np0 > 0) ? rs0 / fmaxf((float)np0 * (float)nneg0, 1.0f) : 0.0f;
        const float rl1 = (np1 > 0) ? rs1 / fmaxf((float)np1 * (float)nneg1, 1.0f) : 0.0f;
        const float hp  = (np0 > 0 ? 1.0f : 0.0f) + (np1 > 0 ? 1.0f : 0.0f);
        atomicAdd(gsum, rl0 + rl1);
        atomicAdd(gcnt, hp);
        __threadfence();
        const unsigned old = atomicAdd(done, 1u);
        if (old == (N / 2) - 1) {  // last block: coherent readback via atomic RMW
            const float Sv = atomicAdd(gsum, 0.0f);
            const float Cv = atomicAdd(gcnt, 0.0f);
            out[0] = (Cv > 0.0f) ? Sv / fmaxf(Cv, 1.0f) : 0.0f;
        }
    }
}

extern "C" void kernel_launch(void* const* d_in, const int* in_sizes, int n_in,
                              void* d_out, int out_size, void* d_ws, size_t ws_size,
                              hipStream_t stream) {
    const float* V      = (const float*)d_in[0];
    const int*   labels = (const int*)d_in[1];
    float* out = (float*)d_out;

    char* ws = (char*)d_ws;
    float*    inv  = (float*)(ws);                     // 4 KB
    float*    gsum = (float*)(ws + 4096);
    float*    gcnt = (float*)(ws + 4096 + 16);
    unsigned* done = (unsigned*)(ws + 4096 + 32);
    ushort*   Vh   = (ushort*)(ws + 8192);             // 1 MB bf16
    float*    sim  = (float*)(ws + 8192 + 1048576);    // 4 MB raw dots

    k_norms  <<<N / 4, 256, 0, stream>>>(V, inv, Vh, gsum, gcnt, done);
    k_gemm   <<<dim3(N / 64, N / 64), 64, 0, stream>>>(Vh, sim);
    k_rowloss<<<N / 2, 256, 0, stream>>>(sim, inv, labels, gsum, gcnt, done, out);
}